// Round 7
// baseline (270.780 us; speedup 1.0000x reference)
//
#include <hip/hip_runtime.h>
#include <hip/hip_bf16.h>

// MultiHeadAttn: B=4, S=2048, D=1024, H=16, HD=64, scale = sqrt(64) = 8
// Pipeline: transpose+cvt W's | GEMM1 qkv (fused x f32->bf16 cvt in A-staging) |
//           flash attn v4 (swapped 32x32) | GEMM2 +bias
// GEMMs use bijective XCD swizzle (T1/m204); flash grid is XCD-aligned via bh%8.

#define S_ 2048
#define D_ 1024

typedef __attribute__((ext_vector_type(4))) float f32x4;
typedef __attribute__((ext_vector_type(16))) float f32x16;
typedef __attribute__((ext_vector_type(8))) short bf16x8;

__device__ __forceinline__ unsigned short f2b(float f) {
  union { float f; unsigned u; } x; x.f = f;
  unsigned r = x.u + 0x7fffu + ((x.u >> 16) & 1u);
  return (unsigned short)(r >> 16);
}
__device__ __forceinline__ float b2f(unsigned short u) {
  union { unsigned u; float f; } x; x.u = ((unsigned)u) << 16; return x.f;
}

__device__ __forceinline__ void gload_lds16(const void* g, void* l) {
  __builtin_amdgcn_global_load_lds(
      (const __attribute__((address_space(1))) unsigned int*)g,
      (__attribute__((address_space(3))) unsigned int*)l, 16, 0, 0);
}

// W [K][N] f32 -> Wt [N][K] bf16
__global__ void transpose_cvt(const float* __restrict__ W, unsigned short* __restrict__ Wt,
                              int K, int N) {
  __shared__ unsigned short tile[32][33];
  int n0 = blockIdx.x * 32, k0 = blockIdx.y * 32;
  int tx = threadIdx.x & 31, ty = threadIdx.x >> 5;  // 32 x 8
  #pragma unroll
  for (int i = 0; i < 32; i += 8)
    tile[ty + i][tx] = f2b(W[(size_t)(k0 + ty + i) * N + n0 + tx]);
  __syncthreads();
  #pragma unroll
  for (int i = 0; i < 32; i += 8)
    Wt[(size_t)(n0 + ty + i) * K + k0 + tx] = tile[tx][ty + i];
}

// ---------------- GEMM: C[M][N] = A[M][K] * Bt[N][K]^T ----------------
// AF32: A is f32, converted to bf16 during reg-staged A-tile write (fused cvt).
// Both launches use gridDim.x == 64 (hardcoded in the swizzle below).
template <bool AF32>
__global__ __launch_bounds__(256) void gemm_bt(const void* __restrict__ Av,
                                               const unsigned short* __restrict__ Bt,
                                               const float* __restrict__ bias,
                                               float* __restrict__ Cf,
                                               unsigned short* __restrict__ Cb,
                                               int M, int N, int K) {
  __shared__ unsigned short As[128 * 32];
  __shared__ unsigned short Bs[128 * 32];
  int tid = threadIdx.x, wave = tid >> 6, lane = tid & 63;

  // bijective XCD swizzle (m204): nwg % 8 == 0 for both launches
  int lin = blockIdx.y * 64 + blockIdx.x;
  int nwg = gridDim.y * 64;
  int qq = nwg >> 3;
  int swz = (lin & 7) * qq + (lin >> 3);
  int bm = swz & 63, bn = swz >> 6;

  int wr = (wave >> 1) * 64, wc = (wave & 1) * 64;
  f32x4 acc[4][4] = {};

  int arow = wave * 32 + (lane >> 2);            // 0..127 (rows arow, arow+16)
  int acol = (lane & 3) * 8;
  const unsigned short* bG0 = Bt + (size_t)(bn * 128 + wave * 32 + (lane >> 2)) * K + acol;
  const unsigned short* bG1 = bG0 + (size_t)16 * K;
  unsigned short* bL0 = Bs + wave * 32 * 32;
  unsigned short* bL1 = bL0 + 16 * 32;
  unsigned short* aW = As + arow * 32 + acol;    // ds_write dest (row, row+16)

  const unsigned short* aB16 = nullptr;
  const float* aF32 = nullptr;
  if constexpr (AF32) aF32 = (const float*)Av + (size_t)(bm * 128 + arow) * K + acol;
  else                aB16 = (const unsigned short*)Av + (size_t)(bm * 128 + arow) * K + acol;

  for (int k0 = 0; k0 < K; k0 += 32) {
    gload_lds16(bG0, bL0); gload_lds16(bG1, bL1);
    bG0 += 32; bG1 += 32;
    if constexpr (AF32) {
      float4 a0 = *(const float4*)aF32;
      float4 a1 = *(const float4*)(aF32 + 4);
      float4 c0 = *(const float4*)(aF32 + (size_t)16 * K);
      float4 c1 = *(const float4*)(aF32 + (size_t)16 * K + 4);
      aF32 += 32;
      unsigned short r[8], s[8];
      r[0]=f2b(a0.x); r[1]=f2b(a0.y); r[2]=f2b(a0.z); r[3]=f2b(a0.w);
      r[4]=f2b(a1.x); r[5]=f2b(a1.y); r[6]=f2b(a1.z); r[7]=f2b(a1.w);
      s[0]=f2b(c0.x); s[1]=f2b(c0.y); s[2]=f2b(c0.z); s[3]=f2b(c0.w);
      s[4]=f2b(c1.x); s[5]=f2b(c1.y); s[6]=f2b(c1.z); s[7]=f2b(c1.w);
      *(uint4*)aW = *(uint4*)r;
      *(uint4*)(aW + 16 * 32) = *(uint4*)s;
    } else {
      gload_lds16(aB16, aW); gload_lds16(aB16 + (size_t)16 * K, aW + 16 * 32);
      aB16 += 32;
    }
    __syncthreads();
    bf16x8 af[4], bf[4];
    #pragma unroll
    for (int i = 0; i < 4; i++)
      af[i] = *(const bf16x8*)&As[(wr + i * 16 + (lane & 15)) * 32 + (lane >> 4) * 8];
    #pragma unroll
    for (int i = 0; i < 4; i++)
      bf[i] = *(const bf16x8*)&Bs[(wc + i * 16 + (lane & 15)) * 32 + (lane >> 4) * 8];
    #pragma unroll
    for (int i = 0; i < 4; i++)
      #pragma unroll
      for (int j = 0; j < 4; j++)
        acc[i][j] = __builtin_amdgcn_mfma_f32_16x16x32_bf16(af[i], bf[j], acc[i][j], 0, 0, 0);
    __syncthreads();
  }

  int row0 = bm * 128 + wr + (lane >> 4) * 4;
  int col0 = bn * 128 + wc + (lane & 15);
  if (Cb) {
    #pragma unroll
    for (int i = 0; i < 4; i++)
      #pragma unroll
      for (int j = 0; j < 4; j++)
        #pragma unroll
        for (int q = 0; q < 4; q++)
          Cb[(size_t)(row0 + i * 16 + q) * N + col0 + j * 16] = f2b(acc[i][j][q]);
  } else {
    #pragma unroll
    for (int i = 0; i < 4; i++)
      #pragma unroll
      for (int j = 0; j < 4; j++) {
        float bv = bias[col0 + j * 16];
        #pragma unroll
        for (int q = 0; q < 4; q++)
          Cf[(size_t)(row0 + i * 16 + q) * N + col0 + j * 16] = acc[i][j][q] + bv;
      }
  }
}

// ---------------- flash attention v4 (best measured: 136 us) ----------------
// grid (64 heads, 16 q-blocks): XCD = bh%8 -> per-XCD K/V = 4MB = L2-resident (T1).
// block 256 = 4 waves x 32 q-rows; KV tile 64, double-buffered.
// S^T = mfma(K, Q^T): lane-local softmax (T12); P^T in regs via cvt_pk+permlane32_swap.
// PV accumulators split by ks2 parity (4 independent MFMA chains).
__global__ __launch_bounds__(256) void flash_attn(const unsigned short* __restrict__ qkv,
                                                  unsigned short* __restrict__ ao) {
  __shared__ unsigned short Ks[2][4096];   // [64 kv][64 d], 16B-slot ^ (row&7) swizzle
  __shared__ unsigned short Vs[2][4096];   // [64 d][64 kv], same swizzle
  int tid = threadIdx.x, wave = tid >> 6, lane = tid & 63;
  int l31 = lane & 31, hi = lane >> 5;
  int bh = blockIdx.x, b = bh >> 4, h = bh & 15;
  const unsigned short* base = qkv + (size_t)b * S_ * 3072 + h * 64;
  const unsigned short* kb = base + 1024;
  const unsigned short* vb = base + 2048;
  int q0 = blockIdx.y * 128 + wave * 32;

  // Q B-frags: qf[ks] = Q[q0+l31][ks*16 + hi*8 .. +8], prescaled by 1/8 (exact)
  bf16x8 qf[4];
  {
    const unsigned short* qp = base + (size_t)(q0 + l31) * 3072 + hi * 8;
    #pragma unroll
    for (int ks = 0; ks < 4; ks++) {
      bf16x8 v = *(const bf16x8*)(qp + ks * 16);
      #pragma unroll
      for (int e = 0; e < 8; e++) v[e] = (short)f2b(0.125f * b2f((unsigned short)v[e]));
      qf[ks] = v;
    }
  }

  // O^T accumulators, split by ks2 parity (summed in epilogue)
  f32x16 o0a = {}, o0b = {}, o1a = {}, o1b = {};
  float mi = -1e30f, li = 0.f;   // li is per-lane partial; cross-lane merge in epilogue

  // K staging: 2 x gload_lds16/wave, linear dest, pre-swizzled source group
  int r_l = lane >> 3;
  int gsrc = (lane & 7) ^ r_l;
  size_t koffA = (size_t)((wave * 2 + 0) * 8 + r_l) * 3072 + gsrc * 8;
  size_t koffB = (size_t)((wave * 2 + 1) * 8 + r_l) * 3072 + gsrc * 8;
  // V staging: thread -> kv=tid&63, d-group=(tid>>6)*16; 2x bf16x8 loads, 16 b16 swizzled writes
  int kvv = tid & 63, dgr = (tid >> 6) * 16;
  bf16x8 vr0, vr1;

  // prologue: stage tile 0
  {
    gload_lds16(kb + koffA, &Ks[0][(wave * 2 + 0) * 512]);
    gload_lds16(kb + koffB, &Ks[0][(wave * 2 + 1) * 512]);
    const unsigned short* vsrc = vb + (size_t)kvv * 3072 + dgr;
    vr0 = *(const bf16x8*)vsrc;
    vr1 = *(const bf16x8*)(vsrc + 8);
    #pragma unroll
    for (int e = 0; e < 16; e++) {
      int d = dgr + e;
      Vs[0][d * 64 + ((((kvv >> 3) ^ (d & 7)) << 3)) + (kvv & 7)] =
          (unsigned short)(e < 8 ? vr0[e] : vr1[e - 8]);
    }
    __syncthreads();
  }

  for (int t = 0; t < 32; ++t) {
    int cur = t & 1;
    int tn = (t + 1) & 31;
    // prefetch next tile: K async -> LDS[cur^1], V -> regs
    {
      const unsigned short* ksrc = kb + (size_t)tn * 64 * 3072;
      gload_lds16(ksrc + koffA, &Ks[cur ^ 1][(wave * 2 + 0) * 512]);
      gload_lds16(ksrc + koffB, &Ks[cur ^ 1][(wave * 2 + 1) * 512]);
      const unsigned short* vsrc = vb + (size_t)(tn * 64 + kvv) * 3072 + dgr;
      vr0 = *(const bf16x8*)vsrc;
      vr1 = *(const bf16x8*)(vsrc + 8);
    }

    const unsigned short* Kc = Ks[cur];
    const unsigned short* Vc = Vs[cur];

    #pragma unroll
    for (int sub = 0; sub < 2; ++sub) {
      // S^T[sub*32 + kv][q] = sum_ks mfma(K-frag, Q-frag)
      f32x16 sA = {};
      __builtin_amdgcn_s_setprio(1);
      #pragma unroll
      for (int ks = 0; ks < 4; ks++) {
        int row = sub * 32 + l31;
        bf16x8 kf = *(const bf16x8*)&Kc[row * 64 + ((((ks << 1) + hi) ^ (row & 7)) << 3)];
        sA = __builtin_amdgcn_mfma_f32_32x32x16_bf16(kf, qf[ks], sA, 0, 0, 0);
      }
      __builtin_amdgcn_s_setprio(0);

      // lane-local online softmax (lane & lane^32 share q=l31; only max is synced)
      float t0 = fmaxf(fmaxf(sA[0], sA[1]), sA[2]);
      float t1 = fmaxf(fmaxf(sA[3], sA[4]), sA[5]);
      float t2 = fmaxf(fmaxf(sA[6], sA[7]), sA[8]);
      float t3 = fmaxf(fmaxf(sA[9], sA[10]), sA[11]);
      float t4 = fmaxf(fmaxf(sA[12], sA[13]), sA[14]);
      float tm = fmaxf(fmaxf(fmaxf(t0, t1), t2), fmaxf(fmaxf(t3, t4), sA[15]));
      tm = fmaxf(tm, __shfl_xor(tm, 32, 64));
      if (__any(tm > mi + 8.f)) {           // defer-max (T13), wave-uniform trigger
        float tnew = fmaxf(mi, tm);
        float fac = __expf(mi - tnew);
        li *= fac; mi = tnew;
        #pragma unroll
        for (int r = 0; r < 16; r++) {
          o0a[r] *= fac; o0b[r] *= fac; o1a[r] *= fac; o1b[r] *= fac;
        }
      }
      float p[16];
      float rs = 0.f;
      #pragma unroll
      for (int r = 0; r < 16; r++) { p[r] = __expf(sA[r] - mi); rs += p[r]; }
      li += rs;   // per-lane partial; partner merged in epilogue (mi is synced)

      // P^T -> bf16 B-frags in-register: 8 cvt_pk + 4 permlane32_swap
      unsigned c0, c1, c2, c3, c4, c5, c6, c7;
      asm("v_cvt_pk_bf16_f32 %0, %1, %2" : "=v"(c0) : "v"(p[0]),  "v"(p[1]));
      asm("v_cvt_pk_bf16_f32 %0, %1, %2" : "=v"(c1) : "v"(p[2]),  "v"(p[3]));
      asm("v_cvt_pk_bf16_f32 %0, %1, %2" : "=v"(c2) : "v"(p[4]),  "v"(p[5]));
      asm("v_cvt_pk_bf16_f32 %0, %1, %2" : "=v"(c3) : "v"(p[6]),  "v"(p[7]));
      asm("v_cvt_pk_bf16_f32 %0, %1, %2" : "=v"(c4) : "v"(p[8]),  "v"(p[9]));
      asm("v_cvt_pk_bf16_f32 %0, %1, %2" : "=v"(c5) : "v"(p[10]), "v"(p[11]));
      asm("v_cvt_pk_bf16_f32 %0, %1, %2" : "=v"(c6) : "v"(p[12]), "v"(p[13]));
      asm("v_cvt_pk_bf16_f32 %0, %1, %2" : "=v"(c7) : "v"(p[14]), "v"(p[15]));
      asm volatile("v_permlane32_swap_b32 %0, %1" : "+v"(c0), "+v"(c2));
      asm volatile("v_permlane32_swap_b32 %0, %1" : "+v"(c1), "+v"(c3));
      asm volatile("v_permlane32_swap_b32 %0, %1" : "+v"(c4), "+v"(c6));
      asm volatile("v_permlane32_swap_b32 %0, %1" : "+v"(c5), "+v"(c7));
      union { unsigned u[4]; bf16x8 v; } P0, P1;
      P0.u[0] = c0; P0.u[1] = c1; P0.u[2] = c2; P0.u[3] = c3;
      P1.u[0] = c4; P1.u[1] = c5; P1.u[2] = c6; P1.u[3] = c7;

      // O^T += V^T P^T  (A-frag from swizzled Vs); split accumulators by ks2
      int slot0 = (sub << 2) + hi;
      int slot1 = (sub << 2) + 2 + hi;
      bf16x8 vA0 = *(const bf16x8*)&Vc[l31 * 64 + ((slot0 ^ (l31 & 7)) << 3)];
      bf16x8 vA1 = *(const bf16x8*)&Vc[(32 + l31) * 64 + ((slot0 ^ (l31 & 7)) << 3)];
      bf16x8 vB0 = *(const bf16x8*)&Vc[l31 * 64 + ((slot1 ^ (l31 & 7)) << 3)];
      bf16x8 vB1 = *(const bf16x8*)&Vc[(32 + l31) * 64 + ((slot1 ^ (l31 & 7)) << 3)];
      __builtin_amdgcn_s_setprio(1);
      o0a = __builtin_amdgcn_mfma_f32_32x32x16_bf16(vA0, P0.v, o0a, 0, 0, 0);
      o1a = __builtin_amdgcn_mfma_f32_32x32x16_bf16(vA1, P0.v, o1a, 0, 0, 0);
      o0b = __builtin_amdgcn_mfma_f32_32x32x16_bf16(vB0, P1.v, o0b, 0, 0, 0);
      o1b = __builtin_amdgcn_mfma_f32_32x32x16_bf16(vB1, P1.v, o1b, 0, 0, 0);
      __builtin_amdgcn_s_setprio(0);
    }

    // late swizzled write of prefetched V into other buffer (T14 split)
    {
      unsigned short* Vd = Vs[cur ^ 1];
      #pragma unroll
      for (int e = 0; e < 16; e++) {
        int d = dgr + e;
        Vd[d * 64 + ((((kvv >> 3) ^ (d & 7)) << 3)) + (kvv & 7)] =
            (unsigned short)(e < 8 ? vr0[e] : vr1[e - 8]);
      }
    }
    __syncthreads();
  }

  // epilogue: merge partner li, combine split accumulators, normalize, store
  li += __shfl_xor(li, 32, 64);
  float inv = 1.f / li;
  unsigned short* aop = ao + (size_t)(b * S_ + q0 + l31) * D_ + h * 64;
  #pragma unroll
  for (int g = 0; g < 4; g++) {
    union { unsigned short s[4]; uint2 u; } w0, w1;
    #pragma unroll
    for (int e = 0; e < 4; e++) {
      w0.s[e] = f2b((o0a[g * 4 + e] + o0b[g * 4 + e]) * inv);
      w1.s[e] = f2b((o1a[g * 4 + e] + o1b[g * 4 + e]) * inv);
    }
    int d = g * 8 + hi * 4;
    *(uint2*)&aop[d] = w0.u;
    *(uint2*)&aop[32 + d] = w1.u;
  }
}

// ---------------- launch ----------------
extern "C" void kernel_launch(void* const* d_in, const int* in_sizes, int n_in,
                              void* d_out, int out_size, void* d_ws, size_t ws_size,
                              hipStream_t stream) {
  const float* x    = (const float*)d_in[0];
  const float* Wqkv = (const float*)d_in[4];
  const float* Wfc  = (const float*)d_in[5];
  const float* bfc  = (const float*)d_in[6];
  float* out = (float*)d_out;

  char* ws = (char*)d_ws;
  unsigned short* qkv   = (unsigned short*)(ws);                         // 48 MiB  [8192][3072]
  unsigned short* ao    = (unsigned short*)(ws + 50331648);              // 16 MiB  [8192][1024]
  unsigned short* wqkvT = (unsigned short*)(ws + 67108864);              // 6 MiB   [3072][1024]
  unsigned short* wfcT  = (unsigned short*)(ws + 73400320);              // 2 MiB   [1024][1024]

  transpose_cvt<<<dim3(96, 32), dim3(256), 0, stream>>>(Wqkv, wqkvT, 1024, 3072);
  transpose_cvt<<<dim3(32, 32), dim3(256), 0, stream>>>(Wfc, wfcT, 1024, 1024);
  gemm_bt<true><<<dim3(64, 24), dim3(256), 0, stream>>>(x, wqkvT, nullptr, nullptr, qkv,
                                                        8192, 3072, 1024);
  flash_attn<<<dim3(64, 16), dim3(256), 0, stream>>>(qkv, ao);
  gemm_bt<false><<<dim3(64, 8), dim3(256), 0, stream>>>(ao, wfcT, bfc, out, nullptr,
                                                        8192, 1024, 1024);
}

// Round 8
// 221.740 us; speedup vs baseline: 1.2212x; 1.2212x over previous
//
#include <hip/hip_runtime.h>
#include <hip/hip_bf16.h>

// MultiHeadAttn: B=4, S=2048, D=1024, H=16, HD=64, scale = sqrt(64) = 8
// Pipeline: cvt x->bf16 | transpose+cvt W's | GEMM1 qkv | flash attn v7 | GEMM2 +bias

#define S_ 2048
#define D_ 1024

typedef __attribute__((ext_vector_type(4))) float f32x4;
typedef __attribute__((ext_vector_type(16))) float f32x16;
typedef __attribute__((ext_vector_type(8))) short bf16x8;

__device__ __forceinline__ unsigned short f2b(float f) {
  union { float f; unsigned u; } x; x.f = f;
  unsigned r = x.u + 0x7fffu + ((x.u >> 16) & 1u);
  return (unsigned short)(r >> 16);
}
__device__ __forceinline__ float b2f(unsigned short u) {
  union { unsigned u; float f; } x; x.u = ((unsigned)u) << 16; return x.f;
}

__device__ __forceinline__ void gload_lds16(const void* g, void* l) {
  __builtin_amdgcn_global_load_lds(
      (const __attribute__((address_space(1))) unsigned int*)g,
      (__attribute__((address_space(3))) unsigned int*)l, 16, 0, 0);
}

// ---------------- conversion kernels ----------------
__global__ void cvt_f32_bf16(const float* __restrict__ in, unsigned short* __restrict__ out, int n) {
  int i = (blockIdx.x * blockDim.x + threadIdx.x) * 8;
  if (i >= n) return;
  float4 a = *(const float4*)&in[i];
  float4 b = *(const float4*)&in[i + 4];
  unsigned short r[8];
  r[0] = f2b(a.x); r[1] = f2b(a.y); r[2] = f2b(a.z); r[3] = f2b(a.w);
  r[4] = f2b(b.x); r[5] = f2b(b.y); r[6] = f2b(b.z); r[7] = f2b(b.w);
  *(uint4*)&out[i] = *(uint4*)r;
}

// W [K][N] f32 -> Wt [N][K] bf16
__global__ void transpose_cvt(const float* __restrict__ W, unsigned short* __restrict__ Wt,
                              int K, int N) {
  __shared__ unsigned short tile[32][33];
  int n0 = blockIdx.x * 32, k0 = blockIdx.y * 32;
  int tx = threadIdx.x & 31, ty = threadIdx.x >> 5;  // 32 x 8
  #pragma unroll
  for (int i = 0; i < 32; i += 8)
    tile[ty + i][tx] = f2b(W[(size_t)(k0 + ty + i) * N + n0 + tx]);
  __syncthreads();
  #pragma unroll
  for (int i = 0; i < 32; i += 8)
    Wt[(size_t)(n0 + ty + i) * K + k0 + tx] = tile[tx][ty + i];
}

// ---------------- GEMM: C[M][N] = A[M][K] * Bt[N][K]^T (R4 config) ----------------
__global__ __launch_bounds__(256) void gemm_bt(const unsigned short* __restrict__ A,
                                               const unsigned short* __restrict__ Bt,
                                               const float* __restrict__ bias,
                                               float* __restrict__ Cf,
                                               unsigned short* __restrict__ Cb,
                                               int M, int N, int K) {
  __shared__ unsigned short As[128 * 32];
  __shared__ unsigned short Bs[128 * 32];
  int tid = threadIdx.x, wave = tid >> 6, lane = tid & 63;
  int bm = blockIdx.x, bn = blockIdx.y;
  int wr = (wave >> 1) * 64, wc = (wave & 1) * 64;
  f32x4 acc[4][4] = {};

  const unsigned short* aG0 = A + (size_t)(bm * 128 + wave * 32 + (lane >> 2)) * K + (lane & 3) * 8;
  const unsigned short* aG1 = aG0 + (size_t)16 * K;
  const unsigned short* bG0 = Bt + (size_t)(bn * 128 + wave * 32 + (lane >> 2)) * K + (lane & 3) * 8;
  const unsigned short* bG1 = bG0 + (size_t)16 * K;
  unsigned short* aL0 = As + wave * 32 * 32;
  unsigned short* aL1 = aL0 + 16 * 32;
  unsigned short* bL0 = Bs + wave * 32 * 32;
  unsigned short* bL1 = bL0 + 16 * 32;

  for (int k0 = 0; k0 < K; k0 += 32) {
    gload_lds16(aG0, aL0); gload_lds16(aG1, aL1);
    gload_lds16(bG0, bL0); gload_lds16(bG1, bL1);
    aG0 += 32; aG1 += 32; bG0 += 32; bG1 += 32;
    __syncthreads();
    bf16x8 af[4], bf[4];
    #pragma unroll
    for (int i = 0; i < 4; i++)
      af[i] = *(const bf16x8*)&As[(wr + i * 16 + (lane & 15)) * 32 + (lane >> 4) * 8];
    #pragma unroll
    for (int i = 0; i < 4; i++)
      bf[i] = *(const bf16x8*)&Bs[(wc + i * 16 + (lane & 15)) * 32 + (lane >> 4) * 8];
    #pragma unroll
    for (int i = 0; i < 4; i++)
      #pragma unroll
      for (int j = 0; j < 4; j++)
        acc[i][j] = __builtin_amdgcn_mfma_f32_16x16x32_bf16(af[i], bf[j], acc[i][j], 0, 0, 0);
    __syncthreads();
  }

  int row0 = bm * 128 + wr + (lane >> 4) * 4;
  int col0 = bn * 128 + wc + (lane & 15);
  if (Cb) {
    #pragma unroll
    for (int i = 0; i < 4; i++)
      #pragma unroll
      for (int j = 0; j < 4; j++)
        #pragma unroll
        for (int q = 0; q < 4; q++)
          Cb[(size_t)(row0 + i * 16 + q) * N + col0 + j * 16] = f2b(acc[i][j][q]);
  } else {
    #pragma unroll
    for (int i = 0; i < 4; i++)
      #pragma unroll
      for (int j = 0; j < 4; j++) {
        float bv = bias[col0 + j * 16];
        #pragma unroll
        for (int q = 0; q < 4; q++)
          Cf[(size_t)(row0 + i * 16 + q) * N + col0 + j * 16] = acc[i][j][q] + bv;
      }
  }
}

// ---------------- flash attention v7: 2 Q-tiles per wave ----------------
// grid (64 heads, 8 q-blocks of 256): XCD = bh%8 -> per-XCD K/V L2-resident (T1).
// block 256 = 4 waves; each wave owns q-rows [q0, q0+32) and [q0+128, q0+160).
// K-frags and V-frags are LDS-read ONCE and used for BOTH Q-tiles (DS/output halved);
// QK and PV each get 2 independent MFMA chains (ILP). Softmax per v4 (T12/T13).
__global__ __launch_bounds__(256) void flash_attn(const unsigned short* __restrict__ qkv,
                                                  unsigned short* __restrict__ ao) {
  __shared__ unsigned short Ks[2][4096];   // [64 kv][64 d], 16B-slot ^ (row&7) swizzle
  __shared__ unsigned short Vs[2][4096];   // [64 d][64 kv], same swizzle
  int tid = threadIdx.x, wave = tid >> 6, lane = tid & 63;
  int l31 = lane & 31, hi = lane >> 5;
  int bh = blockIdx.x, b = bh >> 4, h = bh & 15;
  const unsigned short* base = qkv + (size_t)b * S_ * 3072 + h * 64;
  const unsigned short* kb = base + 1024;
  const unsigned short* vb = base + 2048;
  int q0 = blockIdx.y * 256 + wave * 32;   // tile A; tile B = q0 + 128

  // Q B-frags for both tiles, prescaled by 1/8 (exact)
  bf16x8 qfA[4], qfB[4];
  {
    const unsigned short* qpA = base + (size_t)(q0 + l31) * 3072 + hi * 8;
    const unsigned short* qpB = qpA + (size_t)128 * 3072;
    #pragma unroll
    for (int ks = 0; ks < 4; ks++) {
      bf16x8 va = *(const bf16x8*)(qpA + ks * 16);
      bf16x8 vc = *(const bf16x8*)(qpB + ks * 16);
      #pragma unroll
      for (int e = 0; e < 8; e++) {
        va[e] = (short)f2b(0.125f * b2f((unsigned short)va[e]));
        vc[e] = (short)f2b(0.125f * b2f((unsigned short)vc[e]));
      }
      qfA[ks] = va; qfB[ks] = vc;
    }
  }

  // O^T accumulators: 2 per Q-tile -> 4 independent PV chains
  f32x16 oA0 = {}, oA1 = {}, oB0 = {}, oB1 = {};
  float miA = -1e30f, liA = 0.f, miB = -1e30f, liB = 0.f;

  // K staging: 2 x gload_lds16/wave, linear dest, pre-swizzled source group
  int r_l = lane >> 3;
  int gsrc = (lane & 7) ^ r_l;
  size_t koffA = (size_t)((wave * 2 + 0) * 8 + r_l) * 3072 + gsrc * 8;
  size_t koffB = (size_t)((wave * 2 + 1) * 8 + r_l) * 3072 + gsrc * 8;
  // V staging: thread -> kv=tid&63, d-group=(tid>>6)*16; 2x bf16x8 loads, 16 b16 swizzled writes
  int kvv = tid & 63, dgr = (tid >> 6) * 16;
  bf16x8 vr0, vr1;

  // prologue: stage tile 0
  {
    gload_lds16(kb + koffA, &Ks[0][(wave * 2 + 0) * 512]);
    gload_lds16(kb + koffB, &Ks[0][(wave * 2 + 1) * 512]);
    const unsigned short* vsrc = vb + (size_t)kvv * 3072 + dgr;
    vr0 = *(const bf16x8*)vsrc;
    vr1 = *(const bf16x8*)(vsrc + 8);
    #pragma unroll
    for (int e = 0; e < 16; e++) {
      int d = dgr + e;
      Vs[0][d * 64 + ((((kvv >> 3) ^ (d & 7)) << 3)) + (kvv & 7)] =
          (unsigned short)(e < 8 ? vr0[e] : vr1[e - 8]);
    }
    __syncthreads();
  }

  for (int t = 0; t < 32; ++t) {
    int cur = t & 1;
    int tn = (t + 1) & 31;
    // prefetch next tile: K async -> LDS[cur^1], V -> regs
    {
      const unsigned short* ksrc = kb + (size_t)tn * 64 * 3072;
      gload_lds16(ksrc + koffA, &Ks[cur ^ 1][(wave * 2 + 0) * 512]);
      gload_lds16(ksrc + koffB, &Ks[cur ^ 1][(wave * 2 + 1) * 512]);
      const unsigned short* vsrc = vb + (size_t)(tn * 64 + kvv) * 3072 + dgr;
      vr0 = *(const bf16x8*)vsrc;
      vr1 = *(const bf16x8*)(vsrc + 8);
    }

    const unsigned short* Kc = Ks[cur];
    const unsigned short* Vc = Vs[cur];

    #pragma unroll
    for (int sub = 0; sub < 2; ++sub) {
      // S^T[sub*32 + kv][q] for both Q-tiles; K-frag read once, used twice
      f32x16 sA = {}, sB = {};
      __builtin_amdgcn_s_setprio(1);
      #pragma unroll
      for (int ks = 0; ks < 4; ks++) {
        int row = sub * 32 + l31;
        bf16x8 kf = *(const bf16x8*)&Kc[row * 64 + ((((ks << 1) + hi) ^ (row & 7)) << 3)];
        sA = __builtin_amdgcn_mfma_f32_32x32x16_bf16(kf, qfA[ks], sA, 0, 0, 0);
        sB = __builtin_amdgcn_mfma_f32_32x32x16_bf16(kf, qfB[ks], sB, 0, 0, 0);
      }
      __builtin_amdgcn_s_setprio(0);

      // ---- softmax + P-conversion, Q-tile A ----
      union { unsigned u[4]; bf16x8 v; } PA0, PA1;
      {
        float t0 = fmaxf(fmaxf(sA[0], sA[1]), sA[2]);
        float t1 = fmaxf(fmaxf(sA[3], sA[4]), sA[5]);
        float t2 = fmaxf(fmaxf(sA[6], sA[7]), sA[8]);
        float t3 = fmaxf(fmaxf(sA[9], sA[10]), sA[11]);
        float t4 = fmaxf(fmaxf(sA[12], sA[13]), sA[14]);
        float tm = fmaxf(fmaxf(fmaxf(t0, t1), t2), fmaxf(fmaxf(t3, t4), sA[15]));
        tm = fmaxf(tm, __shfl_xor(tm, 32, 64));
        if (__any(tm > miA + 8.f)) {
          float tnew = fmaxf(miA, tm);
          float fac = __expf(miA - tnew);
          liA *= fac; miA = tnew;
          #pragma unroll
          for (int r = 0; r < 16; r++) { oA0[r] *= fac; oA1[r] *= fac; }
        }
        float p[16];
        float rs = 0.f;
        #pragma unroll
        for (int r = 0; r < 16; r++) { p[r] = __expf(sA[r] - miA); rs += p[r]; }
        liA += rs;
        unsigned c0, c1, c2, c3, c4, c5, c6, c7;
        asm("v_cvt_pk_bf16_f32 %0, %1, %2" : "=v"(c0) : "v"(p[0]),  "v"(p[1]));
        asm("v_cvt_pk_bf16_f32 %0, %1, %2" : "=v"(c1) : "v"(p[2]),  "v"(p[3]));
        asm("v_cvt_pk_bf16_f32 %0, %1, %2" : "=v"(c2) : "v"(p[4]),  "v"(p[5]));
        asm("v_cvt_pk_bf16_f32 %0, %1, %2" : "=v"(c3) : "v"(p[6]),  "v"(p[7]));
        asm("v_cvt_pk_bf16_f32 %0, %1, %2" : "=v"(c4) : "v"(p[8]),  "v"(p[9]));
        asm("v_cvt_pk_bf16_f32 %0, %1, %2" : "=v"(c5) : "v"(p[10]), "v"(p[11]));
        asm("v_cvt_pk_bf16_f32 %0, %1, %2" : "=v"(c6) : "v"(p[12]), "v"(p[13]));
        asm("v_cvt_pk_bf16_f32 %0, %1, %2" : "=v"(c7) : "v"(p[14]), "v"(p[15]));
        asm volatile("v_permlane32_swap_b32 %0, %1" : "+v"(c0), "+v"(c2));
        asm volatile("v_permlane32_swap_b32 %0, %1" : "+v"(c1), "+v"(c3));
        asm volatile("v_permlane32_swap_b32 %0, %1" : "+v"(c4), "+v"(c6));
        asm volatile("v_permlane32_swap_b32 %0, %1" : "+v"(c5), "+v"(c7));
        PA0.u[0] = c0; PA0.u[1] = c1; PA0.u[2] = c2; PA0.u[3] = c3;
        PA1.u[0] = c4; PA1.u[1] = c5; PA1.u[2] = c6; PA1.u[3] = c7;
      }
      // ---- softmax + P-conversion, Q-tile B ----
      union { unsigned u[4]; bf16x8 v; } PB0, PB1;
      {
        float t0 = fmaxf(fmaxf(sB[0], sB[1]), sB[2]);
        float t1 = fmaxf(fmaxf(sB[3], sB[4]), sB[5]);
        float t2 = fmaxf(fmaxf(sB[6], sB[7]), sB[8]);
        float t3 = fmaxf(fmaxf(sB[9], sB[10]), sB[11]);
        float t4 = fmaxf(fmaxf(sB[12], sB[13]), sB[14]);
        float tm = fmaxf(fmaxf(fmaxf(t0, t1), t2), fmaxf(fmaxf(t3, t4), sB[15]));
        tm = fmaxf(tm, __shfl_xor(tm, 32, 64));
        if (__any(tm > miB + 8.f)) {
          float tnew = fmaxf(miB, tm);
          float fac = __expf(miB - tnew);
          liB *= fac; miB = tnew;
          #pragma unroll
          for (int r = 0; r < 16; r++) { oB0[r] *= fac; oB1[r] *= fac; }
        }
        float p[16];
        float rs = 0.f;
        #pragma unroll
        for (int r = 0; r < 16; r++) { p[r] = __expf(sB[r] - miB); rs += p[r]; }
        liB += rs;
        unsigned c0, c1, c2, c3, c4, c5, c6, c7;
        asm("v_cvt_pk_bf16_f32 %0, %1, %2" : "=v"(c0) : "v"(p[0]),  "v"(p[1]));
        asm("v_cvt_pk_bf16_f32 %0, %1, %2" : "=v"(c1) : "v"(p[2]),  "v"(p[3]));
        asm("v_cvt_pk_bf16_f32 %0, %1, %2" : "=v"(c2) : "v"(p[4]),  "v"(p[5]));
        asm("v_cvt_pk_bf16_f32 %0, %1, %2" : "=v"(c3) : "v"(p[6]),  "v"(p[7]));
        asm("v_cvt_pk_bf16_f32 %0, %1, %2" : "=v"(c4) : "v"(p[8]),  "v"(p[9]));
        asm("v_cvt_pk_bf16_f32 %0, %1, %2" : "=v"(c5) : "v"(p[10]), "v"(p[11]));
        asm("v_cvt_pk_bf16_f32 %0, %1, %2" : "=v"(c6) : "v"(p[12]), "v"(p[13]));
        asm("v_cvt_pk_bf16_f32 %0, %1, %2" : "=v"(c7) : "v"(p[14]), "v"(p[15]));
        asm volatile("v_permlane32_swap_b32 %0, %1" : "+v"(c0), "+v"(c2));
        asm volatile("v_permlane32_swap_b32 %0, %1" : "+v"(c1), "+v"(c3));
        asm volatile("v_permlane32_swap_b32 %0, %1" : "+v"(c4), "+v"(c6));
        asm volatile("v_permlane32_swap_b32 %0, %1" : "+v"(c5), "+v"(c7));
        PB0.u[0] = c0; PB0.u[1] = c1; PB0.u[2] = c2; PB0.u[3] = c3;
        PB1.u[0] = c4; PB1.u[1] = c5; PB1.u[2] = c6; PB1.u[3] = c7;
      }

      // O^T += V^T P^T — V-frags read once, used for both Q-tiles
      int slot0 = (sub << 2) + hi;
      int slot1 = (sub << 2) + 2 + hi;
      bf16x8 v00 = *(const bf16x8*)&Vc[l31 * 64 + ((slot0 ^ (l31 & 7)) << 3)];
      bf16x8 v01 = *(const bf16x8*)&Vc[(32 + l31) * 64 + ((slot0 ^ (l31 & 7)) << 3)];
      bf16x8 v10 = *(const bf16x8*)&Vc[l31 * 64 + ((slot1 ^ (l31 & 7)) << 3)];
      bf16x8 v11 = *(const bf16x8*)&Vc[(32 + l31) * 64 + ((slot1 ^ (l31 & 7)) << 3)];
      __builtin_amdgcn_s_setprio(1);
      oA0 = __builtin_amdgcn_mfma_f32_32x32x16_bf16(v00, PA0.v, oA0, 0, 0, 0);
      oB0 = __builtin_amdgcn_mfma_f32_32x32x16_bf16(v00, PB0.v, oB0, 0, 0, 0);
      oA1 = __builtin_amdgcn_mfma_f32_32x32x16_bf16(v01, PA0.v, oA1, 0, 0, 0);
      oB1 = __builtin_amdgcn_mfma_f32_32x32x16_bf16(v01, PB0.v, oB1, 0, 0, 0);
      oA0 = __builtin_amdgcn_mfma_f32_32x32x16_bf16(v10, PA1.v, oA0, 0, 0, 0);
      oB0 = __builtin_amdgcn_mfma_f32_32x32x16_bf16(v10, PB1.v, oB0, 0, 0, 0);
      oA1 = __builtin_amdgcn_mfma_f32_32x32x16_bf16(v11, PA1.v, oA1, 0, 0, 0);
      oB1 = __builtin_amdgcn_mfma_f32_32x32x16_bf16(v11, PB1.v, oB1, 0, 0, 0);
      __builtin_amdgcn_s_setprio(0);
    }

    // late swizzled write of prefetched V into other buffer (T14 split)
    {
      unsigned short* Vd = Vs[cur ^ 1];
      #pragma unroll
      for (int e = 0; e < 16; e++) {
        int d = dgr + e;
        Vd[d * 64 + ((((kvv >> 3) ^ (d & 7)) << 3)) + (kvv & 7)] =
            (unsigned short)(e < 8 ? vr0[e] : vr1[e - 8]);
      }
    }
    __syncthreads();
  }

  // epilogue: merge partner li, normalize, store both Q-tiles
  liA += __shfl_xor(liA, 32, 64);
  liB += __shfl_xor(liB, 32, 64);
  float invA = 1.f / liA, invB = 1.f / liB;
  unsigned short* aopA = ao + (size_t)(b * S_ + q0 + l31) * D_ + h * 64;
  unsigned short* aopB = aopA + (size_t)128 * D_;
  #pragma unroll
  for (int g = 0; g < 4; g++) {
    union { unsigned short s[4]; uint2 u; } wa0, wa1, wb0, wb1;
    #pragma unroll
    for (int e = 0; e < 4; e++) {
      wa0.s[e] = f2b(oA0[g * 4 + e] * invA);
      wa1.s[e] = f2b(oA1[g * 4 + e] * invA);
      wb0.s[e] = f2b(oB0[g * 4 + e] * invB);
      wb1.s[e] = f2b(oB1[g * 4 + e] * invB);
    }
    int d = g * 8 + hi * 4;
    *(uint2*)&aopA[d] = wa0.u;
    *(uint2*)&aopA[32 + d] = wa1.u;
    *(uint2*)&aopB[d] = wb0.u;
    *(uint2*)&aopB[32 + d] = wb1.u;
  }
}

// ---------------- launch ----------------
extern "C" void kernel_launch(void* const* d_in, const int* in_sizes, int n_in,
                              void* d_out, int out_size, void* d_ws, size_t ws_size,
                              hipStream_t stream) {
  const float* x    = (const float*)d_in[0];
  const float* Wqkv = (const float*)d_in[4];
  const float* Wfc  = (const float*)d_in[5];
  const float* bfc  = (const float*)d_in[6];
  float* out = (float*)d_out;

  char* ws = (char*)d_ws;
  unsigned short* xb    = (unsigned short*)(ws);                         // 16 MiB  [8192][1024]
  unsigned short* qkv   = (unsigned short*)(ws + 16777216);              // 48 MiB  [8192][3072]
  unsigned short* ao    = (unsigned short*)(ws + 67108864);              // 16 MiB  [8192][1024]
  unsigned short* wqkvT = (unsigned short*)(ws + 83886080);              // 6 MiB   [3072][1024]
  unsigned short* wfcT  = (unsigned short*)(ws + 90177536);              // 2 MiB   [1024][1024]

  cvt_f32_bf16<<<dim3(4096), dim3(256), 0, stream>>>(x, xb, 8388608);
  transpose_cvt<<<dim3(96, 32), dim3(256), 0, stream>>>(Wqkv, wqkvT, 1024, 3072);
  transpose_cvt<<<dim3(32, 32), dim3(256), 0, stream>>>(Wfc, wfcT, 1024, 1024);
  gemm_bt<<<dim3(64, 24), dim3(256), 0, stream>>>(xb, wqkvT, nullptr, nullptr, qkv, 8192, 3072, 1024);
  flash_attn<<<dim3(64, 8), dim3(256), 0, stream>>>(qkv, ao);
  gemm_bt<<<dim3(64, 8), dim3(256), 0, stream>>>(ao, wfcT, bfc, out, nullptr, 8192, 1024, 1024);
}